// Round 1
// 696.663 us; speedup vs baseline: 1.0355x; 1.0355x over previous
//
#include <hip/hip_runtime.h>
#include <hip/hip_bf16.h>

// Problem dims (fixed)
#define Bdim 16
#define Sdim 512
#define Ddim 512
#define Hdim 8
#define DKdim 64
#define Fdim 2048
#define Mrows (Bdim * Sdim)   // 8192

typedef __attribute__((ext_vector_type(8))) short  frag16;   // 8 bf16 (4 VGPRs)
typedef __attribute__((ext_vector_type(4))) float  f32x4;    // MFMA acc
typedef __attribute__((ext_vector_type(8))) unsigned short ushort8;
typedef __attribute__((ext_vector_type(4))) unsigned short ushort4v;

// round-to-nearest-even fp32 -> bf16 (finite data)
__device__ __forceinline__ unsigned short f2b(float x) {
    union { float f; unsigned int u; } v; v.f = x;
    unsigned int r = (v.u + 0x7FFFu + ((v.u >> 16) & 1u)) >> 16;
    return (unsigned short)r;
}

// ---------------------------------------------------------------------------
// bf16 MFMA GEMM, 128x128 tile (used for FFN1, N=2048)
// ---------------------------------------------------------------------------
__global__ __launch_bounds__(256) void gemm_mfma(
    const __hip_bfloat16* __restrict__ A, const __hip_bfloat16* __restrict__ Bt,
    const float* __restrict__ bias, const float* __restrict__ R,
    float* __restrict__ Cf, unsigned short* __restrict__ Cb,
    int M, int N, int K, int do_relu)
{
    __shared__ short As[128 * 32];
    __shared__ short Bs[128 * 32];

    const int t = threadIdx.x;
    const int lane = t & 63;
    const int wave = t >> 6;
    const int bm = blockIdx.y * 128;
    const int bn = blockIdx.x * 128;
    const int wm = (wave >> 1) * 64;
    const int wn = (wave & 1) * 64;

    f32x4 acc[4][4] = {};
    const int lrow = lane >> 2;
    const int lcol = (lane & 3) * 8;

    for (int k0 = 0; k0 < K; k0 += 32) {
#pragma unroll
        for (int i = 0; i < 2; ++i) {
            const int chunk = wave * 2 + i;
            const int row = chunk * 16 + lrow;
            const __hip_bfloat16* ga = A + (size_t)(bm + row) * K + k0 + lcol;
            const __hip_bfloat16* gb = Bt + (size_t)(bn + row) * K + k0 + lcol;
            __builtin_amdgcn_global_load_lds(
                (const __attribute__((address_space(1))) unsigned int*)ga,
                (__attribute__((address_space(3))) unsigned int*)(As + chunk * 512),
                16, 0, 0);
            __builtin_amdgcn_global_load_lds(
                (const __attribute__((address_space(1))) unsigned int*)gb,
                (__attribute__((address_space(3))) unsigned int*)(Bs + chunk * 512),
                16, 0, 0);
        }
        __syncthreads();

        const int fr = lane & 15;
        const int quad = lane >> 4;
        frag16 af[4], bfr[4];
#pragma unroll
        for (int i = 0; i < 4; ++i) {
            af[i]  = *(const frag16*)(As + (wm + i * 16 + fr) * 32 + quad * 8);
            bfr[i] = *(const frag16*)(Bs + (wn + i * 16 + fr) * 32 + quad * 8);
        }
#pragma unroll
        for (int mi = 0; mi < 4; ++mi)
#pragma unroll
            for (int ni = 0; ni < 4; ++ni)
                acc[mi][ni] = __builtin_amdgcn_mfma_f32_16x16x32_bf16(
                    af[mi], bfr[ni], acc[mi][ni], 0, 0, 0);
        __syncthreads();
    }

    const int fr = lane & 15;
    const int quad = lane >> 4;
#pragma unroll
    for (int mi = 0; mi < 4; ++mi) {
#pragma unroll
        for (int r = 0; r < 4; ++r) {
            const int m = bm + wm + mi * 16 + quad * 4 + r;
#pragma unroll
            for (int ni = 0; ni < 4; ++ni) {
                const int n = bn + wn + ni * 16 + fr;
                float v = acc[mi][ni][r] + bias[n];
                if (R) v += R[(size_t)m * N + n];
                if (do_relu) v = fmaxf(v, 0.f);
                if (Cf) Cf[(size_t)m * N + n] = v;
                if (Cb) Cb[(size_t)m * N + n] = f2b(v);
            }
        }
    }
}

// ---------------------------------------------------------------------------
// bf16 MFMA GEMM, 128x64 tile, N=512 fixed. Dual-mode via blockIdx.z:
// z=0: A0@B0^T+bias0 -> Cb (normal bf16) / Cf(+R) fp32
// z=1: A1@B1^T+bias1 -> CbT transposed Vt[b,h,d,s] bf16
// ---------------------------------------------------------------------------
__global__ __launch_bounds__(256) void gemm_n64(
    const unsigned short* __restrict__ A0, const unsigned short* __restrict__ A1,
    const unsigned short* __restrict__ B0, const unsigned short* __restrict__ B1,
    const float* __restrict__ bias0, const float* __restrict__ bias1,
    const float* __restrict__ R, float* __restrict__ Cf,
    unsigned short* __restrict__ Cb, unsigned short* __restrict__ CbT,
    int K)
{
    const int NN = 512;
    __shared__ short As[128 * 32];
    __shared__ short Bs[64 * 32];

    const int trans = blockIdx.z;
    const unsigned short* A  = trans ? A1 : A0;
    const unsigned short* Bt = trans ? B1 : B0;
    const float* bias        = trans ? bias1 : bias0;

    const int t = threadIdx.x;
    const int lane = t & 63;
    const int wave = t >> 6;
    const int bm = blockIdx.y * 128;
    const int bn = blockIdx.x * 64;
    const int wm = (wave >> 1) * 64;
    const int wn = (wave & 1) * 32;

    f32x4 acc[4][2] = {};
    const int lrow = lane >> 2;
    const int lcol = (lane & 3) * 8;

    for (int k0 = 0; k0 < K; k0 += 32) {
#pragma unroll
        for (int i = 0; i < 2; ++i) {
            const int chunk = wave * 2 + i;
            const int row = chunk * 16 + lrow;
            const unsigned short* ga = A + (size_t)(bm + row) * K + k0 + lcol;
            __builtin_amdgcn_global_load_lds(
                (const __attribute__((address_space(1))) unsigned int*)ga,
                (__attribute__((address_space(3))) unsigned int*)(As + chunk * 512),
                16, 0, 0);
        }
        {
            const int row = wave * 16 + lrow;
            const unsigned short* gb = Bt + (size_t)(bn + row) * K + k0 + lcol;
            __builtin_amdgcn_global_load_lds(
                (const __attribute__((address_space(1))) unsigned int*)gb,
                (__attribute__((address_space(3))) unsigned int*)(Bs + wave * 512),
                16, 0, 0);
        }
        __syncthreads();

        const int fr = lane & 15;
        const int quad = lane >> 4;
        frag16 af[4], bfr[2];
#pragma unroll
        for (int i = 0; i < 4; ++i)
            af[i] = *(const frag16*)(As + (wm + i * 16 + fr) * 32 + quad * 8);
#pragma unroll
        for (int i = 0; i < 2; ++i)
            bfr[i] = *(const frag16*)(Bs + (wn + i * 16 + fr) * 32 + quad * 8);
#pragma unroll
        for (int mi = 0; mi < 4; ++mi)
#pragma unroll
            for (int ni = 0; ni < 2; ++ni)
                acc[mi][ni] = __builtin_amdgcn_mfma_f32_16x16x32_bf16(
                    af[mi], bfr[ni], acc[mi][ni], 0, 0, 0);
        __syncthreads();
    }

    const int fr = lane & 15;
    const int quad = lane >> 4;

    if (trans) {
#pragma unroll
        for (int mi = 0; mi < 4; ++mi)
#pragma unroll
            for (int ni = 0; ni < 2; ++ni) {
                const int m = bm + wm + mi * 16 + quad * 4;
                const int n = bn + wn + ni * 16 + fr;
                ushort4v o;
#pragma unroll
                for (int r = 0; r < 4; ++r) o[r] = f2b(acc[mi][ni][r] + bias[n]);
                const int bb = m >> 9, s = m & 511;
                const int hh = n >> 6, dd = n & 63;
                *(ushort4v*)(CbT + (((size_t)((bb * Hdim + hh) * DKdim + dd)) << 9) + s) = o;
            }
        return;
    }

#pragma unroll
    for (int mi = 0; mi < 4; ++mi) {
#pragma unroll
        for (int r = 0; r < 4; ++r) {
            const int m = bm + wm + mi * 16 + quad * 4 + r;
#pragma unroll
            for (int ni = 0; ni < 2; ++ni) {
                const int n = bn + wn + ni * 16 + fr;
                float v = acc[mi][ni][r] + bias[n];
                if (R) v += R[(size_t)m * NN + n];
                if (Cf) Cf[(size_t)m * NN + n] = v;
                if (Cb) Cb[(size_t)m * NN + n] = f2b(v);
            }
        }
    }
}

// ---------------------------------------------------------------------------
// fp32 -> bf16 convert
// ---------------------------------------------------------------------------
__global__ __launch_bounds__(256) void conv_b(
    const float* __restrict__ X, unsigned short* __restrict__ Y)
{
    const size_t i = ((size_t)blockIdx.x * 256 + threadIdx.x) * 8;
    float4 a = *(const float4*)(X + i);
    float4 b = *(const float4*)(X + i + 4);
    ushort8 o;
    o[0] = f2b(a.x); o[1] = f2b(a.y); o[2] = f2b(a.z); o[3] = f2b(a.w);
    o[4] = f2b(b.x); o[5] = f2b(b.y); o[6] = f2b(b.z); o[7] = f2b(b.w);
    *(ushort8*)(Y + i) = o;
}

// ---------------------------------------------------------------------------
// ALL weight transposes fused: 1600 tiles of 64x64, [K,N] fp32 -> [N,K] bf16
// ---------------------------------------------------------------------------
__global__ __launch_bounds__(256) void wtrans_all(
    const float* __restrict__ Wk, const float* __restrict__ Wv,
    const float* __restrict__ Wo, const float* __restrict__ W1,
    const float* __restrict__ W2, unsigned short* __restrict__ dst)
{
    const int bid = blockIdx.x;
    const float* src; unsigned short* d; int K, N, tk, tn;
    if (bid < 576) {
        const int mat = bid >> 6, tile = bid & 63;
        const int l = mat / 3, wch = mat % 3;
        const float* W = (wch == 0) ? Wk : (wch == 1) ? Wv : Wo;
        src = W + (size_t)l * 262144;
        d = dst + (size_t)mat * 262144;
        K = 512; N = 512; tn = tile & 7; tk = tile >> 3;
    } else if (bid < 1088) {
        const int idx = bid - 576, l2 = idx >> 8, tile = idx & 255;
        src = W1 + (size_t)(l2 * 2) * (512 * 2048);
        d = dst + 9 * 262144 + (size_t)l2 * (512 * 2048);
        K = 512; N = 2048; tn = tile & 31; tk = tile >> 5;
    } else {
        const int idx = bid - 1088, l2 = idx >> 8, tile = idx & 255;
        src = W2 + (size_t)(l2 * 2) * (2048 * 512);
        d = dst + 9 * 262144 + 2 * (512 * 2048) + (size_t)l2 * (2048 * 512);
        K = 2048; N = 512; tn = tile & 7; tk = tile >> 3;
    }
    const int n0 = tn * 64, k0 = tk * 64;
    __shared__ float T[64][65];
    const int t = threadIdx.x;
    const int kl = t >> 4, n4 = (t & 15) << 2;
#pragma unroll
    for (int it = 0; it < 4; ++it) {
        const int k = kl + it * 16;
        float4 v = *(const float4*)(src + (size_t)(k0 + k) * N + n0 + n4);
        T[n4 + 0][k] = v.x; T[n4 + 1][k] = v.y;
        T[n4 + 2][k] = v.z; T[n4 + 3][k] = v.w;
    }
    __syncthreads();
    const int nl = t >> 3, k8 = (t & 7) << 3;
#pragma unroll
    for (int it = 0; it < 2; ++it) {
        const int n = nl + it * 32;
        ushort8 o;
#pragma unroll
        for (int c = 0; c < 8; ++c) o[c] = f2b(T[n][k8 + c]);
        *(ushort8*)(d + (size_t)(n0 + n) * K + k0 + k8) = o;
    }
}

// ---------------------------------------------------------------------------
// Flash-style monotonic attention v3. One WAVE PAIR = 16 q-rows; the two
// waves of a pair split the j-dimension by tile parity (pass 1) / u parity
// (pass 2) and combine sum1/sum2/oacc through LDS. vs v2: 2x waves
// (dim3(16,H,B) x 4 waves = 8 waves/SIMD) for latency hiding, and the
// worst-case serial j-loop per wave is halved.
// Fully-masked row (mask0, i==0): uniform 1/512 over ALL j.
// ---------------------------------------------------------------------------
__global__ __launch_bounds__(256, 8) void attn_flash3(
    const unsigned short* __restrict__ Kb,   // [B*S, D] bf16 (Q == K)
    const unsigned short* __restrict__ Vt,   // [B,H,DK,S] bf16
    const float* __restrict__ gam,
    unsigned short* __restrict__ Ob,         // [B*S, D] bf16
    int mask_type)
{
    __shared__ float CTs[2][16 * 33];            // cross-tile strict suffix (per pair)
    __shared__ unsigned short Pst[4][16 * 36];   // P staging (A-frag layout, per wave)
    __shared__ float S1s[2][2][16];              // sum1 partials [pair][p][row]
    __shared__ float S2s[2][2][16];              // sum2 partials
    __shared__ float OaccS[2][16 * 66];          // oacc combine (stride 66: 2-way banks)

    const int h = blockIdx.y, b = blockIdx.z;
    const int qt = (blockIdx.x + blockIdx.y + blockIdx.z) & 15;   // balance swizzle
    const int t = threadIdx.x, lane = t & 63, w = t >> 6;
    const int pair = w >> 1;                 // which 16-row q-subtile
    const int p = w & 1;                     // j-split parity within the pair
    const int quad = lane >> 4, fr = lane & 15;
    const int q0 = qt * 32 + pair * 16;
    const int iRow = q0 + fr;                // this lane's q row

    const unsigned short* kbase = Kb + (size_t)b * Sdim * Ddim + h * DKdim;

    // Q as B-operand: rows q0+fr
    frag16 aq0 = *(const frag16*)(kbase + (size_t)(q0 + fr) * Ddim + quad * 8);
    frag16 aq1 = *(const frag16*)(kbase + (size_t)(q0 + fr) * Ddim + 32 + quad * 8);

    float* CTw = CTs[pair];
    const int jnmax = (q0 + 15) >> 4;

    // ---- Pass 1: sum1 partials + per-tile totals into CT (tiles split by parity)
    float psum = 0.f;
    for (int jn = p; jn <= jnmax; jn += 2) {
        frag16 k0 = *(const frag16*)(kbase + (size_t)(jn * 16 + fr) * Ddim + quad * 8);
        frag16 k1 = *(const frag16*)(kbase + (size_t)(jn * 16 + fr) * Ddim + 32 + quad * 8);
        f32x4 z = {0.f, 0.f, 0.f, 0.f};
        z = __builtin_amdgcn_mfma_f32_16x16x32_bf16(k0, aq0, z, 0, 0, 0);
        z = __builtin_amdgcn_mfma_f32_16x16x32_bf16(k1, aq1, z, 0, 0, 0);
        const int jbase = jn * 16 + quad * 4;
        float tq = 0.f;
#pragma unroll
        for (int r = 0; r < 4; ++r) {
            const int j = jbase + r;
            const bool valid = mask_type ? (j <= iRow) : (j < iRow);
            tq += valid ? __expf(z[r] * 0.125f) : 0.f;
        }
        psum += tq;
        float tt = tq;
        tt += __shfl_xor(tt, 16);
        tt += __shfl_xor(tt, 32);
        if (quad == 0) CTw[fr * 33 + jn] = tt;
    }
    {
        float s1 = psum;
        s1 += __shfl_xor(s1, 16);
        s1 += __shfl_xor(s1, 32);
        if (lane < 16) S1s[pair][p][lane] = s1;
    }
    __syncthreads();

    // totals -> strict cross-tile suffix (p==0 wave of each pair; rows by lanes 0..15)
    if (p == 0 && lane < 16) {
        float run = 0.f;
        for (int jn = 31; jn >= 0; --jn) {
            const float tv = (jn <= jnmax) ? CTw[lane * 33 + jn] : 0.f;
            CTw[lane * 33 + jn] = run;
            run += tv;
        }
    }
    __syncthreads();

    const float rsum1 = 1.f / (S1s[pair][0][fr] + S1s[pair][1][fr]);  // inf iff fully masked
    const float gneg = -log1pf(__expf(gam[h]));   // -softplus(gamma)

    // ---- Pass 2: independent u-tiles split by parity, online PV
    unsigned short* Pw = Pst[w];
    const unsigned short* vtb = Vt + (size_t)(b * Hdim + h) * DKdim * Sdim;
    const bool fm_pair = (mask_type == 0) && (q0 == 0);
    const bool fmrow = (mask_type == 0) && (iRow == 0);
    const int umax = fm_pair ? (Sdim / 32 - 1) : ((q0 + 15) >> 5);
    float sum2p = 0.f;
    f32x4 oacc[4] = {};

    for (int u = umax - p; u >= 0; u -= 2) {
#pragma unroll
        for (int half = 0; half < 2; ++half) {
            const int jn = 2 * u + half;
            frag16 k0 = *(const frag16*)(kbase + (size_t)(jn * 16 + fr) * Ddim + quad * 8);
            frag16 k1 = *(const frag16*)(kbase + (size_t)(jn * 16 + fr) * Ddim + 32 + quad * 8);
            f32x4 z = {0.f, 0.f, 0.f, 0.f};
            z = __builtin_amdgcn_mfma_f32_16x16x32_bf16(k0, aq0, z, 0, 0, 0);
            z = __builtin_amdgcn_mfma_f32_16x16x32_bf16(k1, aq1, z, 0, 0, 0);
            const int jbase = jn * 16 + quad * 4;
            float s[4], e1[4], lsuf[4];
            float tq = 0.f;
#pragma unroll
            for (int r = 3; r >= 0; --r) {
                lsuf[r] = tq;                      // strict suffix within 4-run
                const int j = jbase + r;
                const bool valid = mask_type ? (j <= iRow) : (j < iRow);
                s[r] = z[r] * 0.125f;
                e1[r] = valid ? __expf(s[r]) : 0.f;
                tq += e1[r];
            }
            // strict suffix over quads (2 guarded shfl_down)
            float incl = tq;
            {
                float u1 = __shfl_down(incl, 16);
                incl += (quad < 3) ? u1 : 0.f;
                float u2 = __shfl_down(incl, 32);
                incl += (quad < 2) ? u2 : 0.f;
            }
            const float qsuf = incl - tq;
            const float ct = CTw[fr * 33 + jn];
            ushort4v pk;
#pragma unroll
            for (int r = 0; r < 4; ++r) {
                const int j = jbase + r;
                const bool valid = mask_type ? (j <= iRow) : (j < iRow);
                const float suf = ct + qsuf + lsuf[r];
                const float ratio = suf * rsum1;
                const int dd = iRow - j;
                const float pos = (float)(dd >= 0 ? dd : -dd);
                const float arg = (ratio > 0.f) ? ratio * pos : 0.f;   // NaN-safe
                const float te = fminf(fmaxf(__expf(gneg * sqrtf(arg)), 1e-5f), 1e5f);
                const float e2 = valid ? __expf(s[r] * te) : (fmrow ? 1.f : 0.f);
                sum2p += e2;
                pk[r] = f2b(e2);
            }
            *(ushort4v*)(Pw + fr * 36 + half * 16 + quad * 4) = pk;
        }
        // PV over this pair's 32-wide window (A = P from LDS, B = Vt)
        frag16 pf = *(const frag16*)(Pw + fr * 36 + quad * 8);
        const int jb = u * 32;
#pragma unroll
        for (int dt = 0; dt < 4; ++dt) {
            frag16 vf = *(const frag16*)(vtb + (size_t)(dt * 16 + fr) * Sdim + jb + quad * 8);
            oacc[dt] = __builtin_amdgcn_mfma_f32_16x16x32_bf16(pf, vf, oacc[dt], 0, 0, 0);
        }
    }

    // ---- combine the pair's partials
    {
        float s2 = sum2p;
        s2 += __shfl_xor(s2, 16);
        s2 += __shfl_xor(s2, 32);
        if (lane < 16) S2s[pair][p][lane] = s2;
    }
    if (p == 1) {
        float* Os = OaccS[pair];
#pragma unroll
        for (int dt = 0; dt < 4; ++dt)
#pragma unroll
            for (int r = 0; r < 4; ++r)
                Os[(quad * 4 + r) * 66 + dt * 16 + fr] = oacc[dt][r];
    }
    __syncthreads();

    if (p == 0) {
        const float* Os = OaccS[pair];
        const float rs2 = 1.f / (S2s[pair][0][fr] + S2s[pair][1][fr]);   // for row fr
        float rs2q[4];
#pragma unroll
        for (int r = 0; r < 4; ++r) rs2q[r] = __shfl(rs2, quad * 4 + r);

        // O rows q0+quad*4+r, cols dt*16+fr
        unsigned short* obase = Ob + ((size_t)(b * Sdim + q0)) * Ddim + h * DKdim;
#pragma unroll
        for (int dt = 0; dt < 4; ++dt)
#pragma unroll
            for (int r = 0; r < 4; ++r) {
                const float v = oacc[dt][r] + Os[(quad * 4 + r) * 66 + dt * 16 + fr];
                obase[(size_t)(quad * 4 + r) * Ddim + dt * 16 + fr] = f2b(v * rs2q[r]);
            }
    }
}

// ---------------------------------------------------------------------------
// LayerNorm over last dim (512); fp32 out (nullable) + bf16 out (nullable).
// ---------------------------------------------------------------------------
__global__ __launch_bounds__(256) void ln_kernel(
    const float* __restrict__ X, const float* __restrict__ g,
    const float* __restrict__ bta, float* __restrict__ Y,
    unsigned short* __restrict__ Yb)
{
    const int row = blockIdx.x;
    const int t = threadIdx.x;
    __shared__ float r1[256], r2[256];
    const float* x = X + (size_t)row * Ddim;
    float a = x[t], b = x[t + 256];
    r1[t] = a + b;
    r2[t] = a * a + b * b;
    __syncthreads();
    for (int off = 128; off; off >>= 1) {
        if (t < off) { r1[t] += r1[t + off]; r2[t] += r2[t + off]; }
        __syncthreads();
    }
    float mean = r1[0] * (1.f / Ddim);
    float var = r2[0] * (1.f / Ddim) - mean * mean;
    float rs = rsqrtf(var + 1e-5f);
    float y0 = (a - mean) * rs * g[t] + bta[t];
    float y1 = (b - mean) * rs * g[t + 256] + bta[t + 256];
    if (Y) {
        float* y = Y + (size_t)row * Ddim;
        y[t] = y0;
        y[t + 256] = y1;
    }
    if (Yb) {
        unsigned short* yb = Yb + (size_t)row * Ddim;
        yb[t] = f2b(y0);
        yb[t + 256] = f2b(y1);
    }
}

// ---------------------------------------------------------------------------
extern "C" void kernel_launch(void* const* d_in, const int* in_sizes, int n_in,
                              void* d_out, int out_size, void* d_ws, size_t ws_size,
                              hipStream_t stream)
{
    const float* x0     = (const float*)d_in[0];
    const float* y0     = (const float*)d_in[1];
    const float* Wk     = (const float*)d_in[2];
    const float* bk     = (const float*)d_in[3];
    const float* Wv     = (const float*)d_in[4];
    const float* bv     = (const float*)d_in[5];
    const float* Wo     = (const float*)d_in[6];
    const float* bo     = (const float*)d_in[7];
    const float* gammas = (const float*)d_in[8];
    const float* ln1g   = (const float*)d_in[9];
    const float* ln1b   = (const float*)d_in[10];
    const float* W1     = (const float*)d_in[11];
    const float* b1     = (const float*)d_in[12];
    const float* W2     = (const float*)d_in[13];
    const float* b2     = (const float*)d_in[14];
    const float* ln2g   = (const float*)d_in[15];
    const float* ln2b   = (const float*)d_in[16];

    const size_t NBSD = (size_t)Mrows * Ddim;   // 4,194,304
    float* ws = (float*)d_ws;
    float* T1   = ws;
    float* X1   = T1 + NBSD;
    float* Xbuf = X1 + NBSD;
    unsigned short* Kbf = (unsigned short*)(Xbuf + NBSD);
    unsigned short* Vt  = Kbf + NBSD;
    unsigned short* AOb = Vt + NBSD;
    unsigned short* Abf = AOb + NBSD;
    unsigned short* Xbf = Abf + NBSD;
    unsigned short* Ybf = Xbf + NBSD;
    unsigned short* Hbb = Ybf + NBSD;                       // [M,F]
    unsigned short* WtAll = Hbb + (size_t)Mrows * Fdim;

    auto WtK = [&](int l) { return WtAll + (size_t)(l * 3 + 0) * 262144; };
    auto WtV = [&](int l) { return WtAll + (size_t)(l * 3 + 1) * 262144; };
    auto WtO = [&](int l) { return WtAll + (size_t)(l * 3 + 2) * 262144; };
    auto Wt1 = [&](int l) { return WtAll + 9 * 262144 + (size_t)(l >> 1) * (512 * 2048); };
    auto Wt2 = [&](int l) { return WtAll + 9 * 262144 + 2 * (512 * 2048) + (size_t)(l >> 1) * (2048 * 512); };

    const int convBlocks = (int)(NBSD / 2048);

    wtrans_all<<<1600, 256, 0, stream>>>(Wk, Wv, Wo, W1, W2, WtAll);

    auto run_block = [&](int l, const float* qinf, const unsigned short* qinb,
                         const unsigned short* vinb, int mask_type, bool ffn,
                         float* outf, unsigned short* outb) {
        const float* bk_l = bk + (size_t)l * Ddim;
        const float* bv_l = bv + (size_t)l * Ddim;
        const float* bo_l = bo + (size_t)l * Ddim;

        // K (=Q) + V projections in one launch (z=0: K->Kbf, z=1: V->Vt)
        gemm_n64<<<dim3(8, 64, 2), 256, 0, stream>>>(
            qinb, vinb, WtK(l), WtV(l), bk_l, bv_l,
            nullptr, nullptr, Kbf, Vt, Ddim);
        // attention (flash-style streaming, wave-pair j-split)
        attn_flash3<<<dim3(Sdim / 32, Hdim, Bdim), 256, 0, stream>>>(
            Kbf, Vt, gammas + (size_t)l * Hdim, AOb, mask_type);
        // O-projection + residual -> T1 (fp32); LN1
        gemm_n64<<<dim3(8, 64, 1), 256, 0, stream>>>(
            AOb, AOb, WtO(l), WtO(l), bo_l, bo_l,
            qinf, T1, nullptr, nullptr, Ddim);
        float* x1f = ffn ? X1 : outf;
        unsigned short* x1b = ffn ? Abf : outb;
        ln_kernel<<<Mrows, 256, 0, stream>>>(T1,
            ln1g + (size_t)l * Ddim, ln1b + (size_t)l * Ddim, x1f, x1b);
        if (ffn) {
            const float* b1_l = b1 + (size_t)l * Fdim;
            const float* b2_l = b2 + (size_t)l * Ddim;
            gemm_mfma<<<dim3(Fdim / 128, Mrows / 128), 256, 0, stream>>>(
                (const __hip_bfloat16*)Abf, (const __hip_bfloat16*)Wt1(l),
                b1_l, nullptr, nullptr, Hbb, Mrows, Fdim, Ddim, 1);
            gemm_n64<<<dim3(8, 64, 1), 256, 0, stream>>>(
                Hbb, Hbb, Wt2(l), Wt2(l), b2_l, b2_l,
                X1, T1, nullptr, nullptr, Fdim);
            ln_kernel<<<Mrows, 256, 0, stream>>>(T1,
                ln2g + (size_t)l * Ddim, ln2b + (size_t)l * Ddim, outf, outb);
        }
    };

    // Block 0: knowledge encoder (y), mask1, FFN -> Ybf (bf16 only)
    conv_b<<<convBlocks, 256, 0, stream>>>(y0, Abf);
    run_block(0, y0, Abf, Abf, 1, true, nullptr, Ybf);
    // Block 1: question encoder (x), mask1, no FFN -> Xbuf/Xbf
    conv_b<<<convBlocks, 256, 0, stream>>>(x0, Abf);
    run_block(1, x0, Abf, Abf, 1, false, Xbuf, Xbf);
    // Block 2: knowledge retriever, q/k=x, v=y, mask0, FFN -> d_out (fp32)
    run_block(2, Xbuf, Xbf, Ybf, 0, true, (float*)d_out, nullptr);
}